// Round 1
// baseline (528.534 us; speedup 1.0000x reference)
//
#include <hip/hip_runtime.h>
#include <hip/hip_bf16.h>
#include <stdint.h>
#include <math.h>

typedef unsigned short u16;
typedef unsigned int   u32;
typedef __attribute__((ext_vector_type(8))) __bf16 bf16x8;   // 4 VGPRs: MFMA A/B frag
typedef __attribute__((ext_vector_type(8))) u16    u16x8;
typedef __attribute__((ext_vector_type(4))) float  f32x4;

#define BM 128
#define BN 128
#define BK 32

// ---------------------------------------------------------------------------
// fp32 -> bf16 (round-to-nearest-even)
__device__ __forceinline__ u16 f2bf_rne(float f) {
    u32 u = __float_as_uint(f);
    u += 0x7fffu + ((u >> 16) & 1u);
    return (u16)(u >> 16);
}

// sign(w) in bf16: w > 0 ? +1.0 : -1.0  (matches jnp.where(x > 0, 1, -1))
__device__ __forceinline__ u16 signbf(float f) {
    return (f > 0.0f) ? (u16)0x3F80u : (u16)0xBF80u;
}

__global__ void cvt_x_bf16(const float* __restrict__ in, u16* __restrict__ out, long n) {
    long i0 = ((long)blockIdx.x * blockDim.x + threadIdx.x) * 8;
    long stride = (long)gridDim.x * blockDim.x * 8;
    for (long i = i0; i < n; i += stride) {
        f32x4 a = *(const f32x4*)(in + i);
        f32x4 b = *(const f32x4*)(in + i + 4);
        u16x8 o;
        o[0] = f2bf_rne(a[0]); o[1] = f2bf_rne(a[1]);
        o[2] = f2bf_rne(a[2]); o[3] = f2bf_rne(a[3]);
        o[4] = f2bf_rne(b[0]); o[5] = f2bf_rne(b[1]);
        o[6] = f2bf_rne(b[2]); o[7] = f2bf_rne(b[3]);
        *(u16x8*)(out + i) = o;
    }
}

__global__ void cvt_w_sign(const float* __restrict__ in, u16* __restrict__ out, long n) {
    long i0 = ((long)blockIdx.x * blockDim.x + threadIdx.x) * 8;
    long stride = (long)gridDim.x * blockDim.x * 8;
    for (long i = i0; i < n; i += stride) {
        f32x4 a = *(const f32x4*)(in + i);
        f32x4 b = *(const f32x4*)(in + i + 4);
        u16x8 o;
        o[0] = signbf(a[0]); o[1] = signbf(a[1]);
        o[2] = signbf(a[2]); o[3] = signbf(a[3]);
        o[4] = signbf(b[0]); o[5] = signbf(b[1]);
        o[6] = signbf(b[2]); o[7] = signbf(b[3]);
        *(u16x8*)(out + i) = o;
    }
}

// ---------------------------------------------------------------------------
// async global -> LDS, 16B per lane. LDS dest must be uniform_base + lane*16.
__device__ __forceinline__ void gload_lds16(const void* g, void* l) {
    __builtin_amdgcn_global_load_lds(
        (const __attribute__((address_space(1))) void*)g,
        (__attribute__((address_space(3))) void*)l, 16, 0, 0);
}

// ---------------------------------------------------------------------------
// C[M][N] = A[M][K](bf16) * B[N][K](bf16)^T * scale  -- m97 structure:
// 128x128 block tile, BK=32, 4 waves (2x2), each wave 64x64 via 4x4 frags of
// 16x16x32 bf16 MFMA. Staging via global_load_lds width=16 (no LDS padding —
// required by the uniform-base+lane*16 constraint).
__global__ __launch_bounds__(256, 2)
void gemm_bt_bf16(const u16* __restrict__ A, const u16* __restrict__ B,
                  float* __restrict__ C, int M, int N, int K, float scale)
{
    __shared__ u16 As[BM * BK];   // 8 KiB
    __shared__ u16 Bs[BN * BK];   // 8 KiB

    const int tid  = threadIdx.x;
    const int wave = tid >> 6;
    const int lane = tid & 63;

    const int brow = blockIdx.y * BM;
    const int bcol = blockIdx.x * BN;

    const int wrow = (wave >> 1) * 64;   // wave's 64x64 subtile
    const int wcol = (wave & 1) * 64;

    f32x4 acc[4][4];
#pragma unroll
    for (int i = 0; i < 4; ++i)
#pragma unroll
        for (int j = 0; j < 4; ++j) acc[i][j] = (f32x4){0.f, 0.f, 0.f, 0.f};

    // staging map: lane l of wave w -> row w*16 + l/4 (+64 second issue),
    // 8 elems (16B) at col (l%4)*8. LDS offset = wave*1024B + lane*16B. ✓
    const int srow = wave * 16 + (lane >> 2);
    const int scol = (lane & 3) * 8;
    const u16* Ag = A + (size_t)(brow + srow) * K + scol;
    const u16* Bg = B + (size_t)(bcol + srow) * K + scol;
    u16* Asl = &As[srow * BK + scol];
    u16* Bsl = &Bs[srow * BK + scol];

    // MFMA fragment map (16x16x32): A[m=lane&15][k=(lane>>4)*8 + j]
    const int fm = lane & 15;
    const int fk = (lane >> 4) * 8;

    const int ktiles = K / BK;
    for (int kt = 0; kt < ktiles; ++kt) {
        const u16* ag = Ag + kt * BK;
        const u16* bg = Bg + kt * BK;
        gload_lds16(ag,                  Asl);
        gload_lds16(ag + (size_t)64 * K, Asl + 64 * BK);
        gload_lds16(bg,                  Bsl);
        gload_lds16(bg + (size_t)64 * K, Bsl + 64 * BK);
        __syncthreads();   // implies vmcnt(0): staging landed

        bf16x8 af[4], bv[4];
#pragma unroll
        for (int i = 0; i < 4; ++i)
            af[i] = *(const bf16x8*)&As[(wrow + i * 16 + fm) * BK + fk];
#pragma unroll
        for (int j = 0; j < 4; ++j)
            bv[j] = *(const bf16x8*)&Bs[(wcol + j * 16 + fm) * BK + fk];
#pragma unroll
        for (int i = 0; i < 4; ++i)
#pragma unroll
            for (int j = 0; j < 4; ++j)
                acc[i][j] = __builtin_amdgcn_mfma_f32_16x16x32_bf16(
                    af[i], bv[j], acc[i][j], 0, 0, 0);
        __syncthreads();   // protect LDS before next staging
    }

    // C/D layout: col = lane&15, row = (lane>>4)*4 + reg
    const int crow = brow + wrow + (lane >> 4) * 4;
    const int ccol = bcol + wcol + fm;
#pragma unroll
    for (int i = 0; i < 4; ++i)
#pragma unroll
        for (int j = 0; j < 4; ++j)
#pragma unroll
            for (int r = 0; r < 4; ++r)
                C[(size_t)(crow + i * 16 + r) * N + (ccol + j * 16)] =
                    acc[i][j][r] * scale;
}

// ---------------------------------------------------------------------------
// Fallback if workspace too small: same tiling, convert fp32->bf16 / sign
// during LDS staging (regular loads + ds_write). Slower but correct.
__global__ __launch_bounds__(256, 2)
void gemm_fused(const float* __restrict__ A32, const float* __restrict__ W32,
                float* __restrict__ C, int M, int N, int K, float scale)
{
    __shared__ u16 As[BM * BK];
    __shared__ u16 Bs[BN * BK];

    const int tid  = threadIdx.x;
    const int wave = tid >> 6;
    const int lane = tid & 63;

    const int brow = blockIdx.y * BM;
    const int bcol = blockIdx.x * BN;
    const int wrow = (wave >> 1) * 64;
    const int wcol = (wave & 1) * 64;

    f32x4 acc[4][4];
#pragma unroll
    for (int i = 0; i < 4; ++i)
#pragma unroll
        for (int j = 0; j < 4; ++j) acc[i][j] = (f32x4){0.f, 0.f, 0.f, 0.f};

    // staging: thread t handles row t/2, 16 consecutive floats at col (t&1)*16
    const int srow = tid >> 1;
    const int scol = (tid & 1) * 16;
    const float* Ag = A32 + (size_t)(brow + srow) * K + scol;
    const float* Wg = W32 + (size_t)(bcol + srow) * K + scol;
    u16* Asl = &As[srow * BK + scol];
    u16* Bsl = &Bs[srow * BK + scol];

    const int fm = lane & 15;
    const int fk = (lane >> 4) * 8;

    const int ktiles = K / BK;
    for (int kt = 0; kt < ktiles; ++kt) {
        const float* ag = Ag + kt * BK;
        const float* wg = Wg + kt * BK;
        f32x4 a0 = *(const f32x4*)(ag + 0),  a1 = *(const f32x4*)(ag + 4);
        f32x4 a2 = *(const f32x4*)(ag + 8),  a3 = *(const f32x4*)(ag + 12);
        f32x4 w0 = *(const f32x4*)(wg + 0),  w1 = *(const f32x4*)(wg + 4);
        f32x4 w2 = *(const f32x4*)(wg + 8),  w3 = *(const f32x4*)(wg + 12);
        u16x8 pa0, pa1, pw0, pw1;
        pa0[0]=f2bf_rne(a0[0]); pa0[1]=f2bf_rne(a0[1]); pa0[2]=f2bf_rne(a0[2]); pa0[3]=f2bf_rne(a0[3]);
        pa0[4]=f2bf_rne(a1[0]); pa0[5]=f2bf_rne(a1[1]); pa0[6]=f2bf_rne(a1[2]); pa0[7]=f2bf_rne(a1[3]);
        pa1[0]=f2bf_rne(a2[0]); pa1[1]=f2bf_rne(a2[1]); pa1[2]=f2bf_rne(a2[2]); pa1[3]=f2bf_rne(a2[3]);
        pa1[4]=f2bf_rne(a3[0]); pa1[5]=f2bf_rne(a3[1]); pa1[6]=f2bf_rne(a3[2]); pa1[7]=f2bf_rne(a3[3]);
        pw0[0]=signbf(w0[0]); pw0[1]=signbf(w0[1]); pw0[2]=signbf(w0[2]); pw0[3]=signbf(w0[3]);
        pw0[4]=signbf(w1[0]); pw0[5]=signbf(w1[1]); pw0[6]=signbf(w1[2]); pw0[7]=signbf(w1[3]);
        pw1[0]=signbf(w2[0]); pw1[1]=signbf(w2[1]); pw1[2]=signbf(w2[2]); pw1[3]=signbf(w2[3]);
        pw1[4]=signbf(w3[0]); pw1[5]=signbf(w3[1]); pw1[6]=signbf(w3[2]); pw1[7]=signbf(w3[3]);
        *(u16x8*)Asl = pa0;  *(u16x8*)(Asl + 8) = pa1;
        *(u16x8*)Bsl = pw0;  *(u16x8*)(Bsl + 8) = pw1;
        __syncthreads();

        bf16x8 af[4], bv[4];
#pragma unroll
        for (int i = 0; i < 4; ++i)
            af[i] = *(const bf16x8*)&As[(wrow + i * 16 + fm) * BK + fk];
#pragma unroll
        for (int j = 0; j < 4; ++j)
            bv[j] = *(const bf16x8*)&Bs[(wcol + j * 16 + fm) * BK + fk];
#pragma unroll
        for (int i = 0; i < 4; ++i)
#pragma unroll
            for (int j = 0; j < 4; ++j)
                acc[i][j] = __builtin_amdgcn_mfma_f32_16x16x32_bf16(
                    af[i], bv[j], acc[i][j], 0, 0, 0);
        __syncthreads();
    }

    const int crow = brow + wrow + (lane >> 4) * 4;
    const int ccol = bcol + wcol + fm;
#pragma unroll
    for (int i = 0; i < 4; ++i)
#pragma unroll
        for (int j = 0; j < 4; ++j)
#pragma unroll
            for (int r = 0; r < 4; ++r)
                C[(size_t)(crow + i * 16 + r) * N + (ccol + j * 16)] =
                    acc[i][j][r] * scale;
}

// ---------------------------------------------------------------------------
extern "C" void kernel_launch(void* const* d_in, const int* in_sizes, int n_in,
                              void* d_out, int out_size, void* d_ws, size_t ws_size,
                              hipStream_t stream)
{
    const float* x = (const float*)d_in[0];   // [M][K] fp32
    const float* w = (const float*)d_in[1];   // [N][K] fp32
    float* out = (float*)d_out;               // [M][N] fp32

    const int K = 4096;
    const int M = in_sizes[0] / K;            // 8192
    const int N = in_sizes[1] / K;            // 4096
    const float scale = 1.0f / sqrtf((float)K);

    const size_t xbytes = (size_t)M * K * sizeof(u16);
    const size_t wbytes = (size_t)N * K * sizeof(u16);

    dim3 grid(N / BN, M / BM);
    dim3 block(256);

    if (ws_size >= xbytes + wbytes) {
        u16* xb = (u16*)d_ws;
        u16* wb = (u16*)((char*)d_ws + xbytes);
        const long nx = (long)M * K;
        const long nw = (long)N * K;
        int gx = (int)((nx / 8 + 255) / 256);
        int gw = (int)((nw / 8 + 255) / 256);
        cvt_x_bf16<<<dim3(gx), block, 0, stream>>>(x, xb, nx);
        cvt_w_sign<<<dim3(gw), block, 0, stream>>>(w, wb, nw);
        gemm_bt_bf16<<<grid, block, 0, stream>>>(xb, wb, out, M, N, K, scale);
    } else {
        gemm_fused<<<grid, block, 0, stream>>>(x, w, out, M, N, K, scale);
    }
}